// Round 1
// baseline (471.109 us; speedup 1.0000x reference)
//
#include <hip/hip_runtime.h>

#define TT 100
#define HH 100
#define NL 5
#define NOUT 10
#define NG 400  // 4*H gate rows

// One block per layer, wavefront-pipelined over timesteps.
// Thread r<400 owns gate row r: Wih row + Whh row live in VGPRs for all 100 steps.
__launch_bounds__(512, 2)
__global__ void lstm_pipe_kernel(
    const float* __restrict__ input,   // [T, H]
    const float* __restrict__ Wih,     // [L, 4H, H]
    const float* __restrict__ Whh,     // [L, 4H, H]
    const float* __restrict__ bih,     // [L, 4H]
    const float* __restrict__ bhh,     // [L, 4H]
    const float* __restrict__ Wout,    // [OUT, H]
    const float* __restrict__ bout,    // [OUT]
    float* __restrict__ out,           // [T, OUT]
    int* __restrict__ flags,           // [L-1, T] producer->consumer ready flags
    float* __restrict__ xstage)        // [L-1, T, H] inter-layer activations
{
  const int l = blockIdx.x;
  const int tid = threadIdx.x;

  __shared__ __align__(16) float xbuf[HH];   // x_t for this layer
  __shared__ __align__(16) float hbuf[HH];   // h_{t-1} -> h_t
  __shared__ __align__(16) float gact[NG];   // activated gates
  __shared__ __align__(16) float pacc[256];  // projection partials (layer 4)

  // ---- persistent per-thread state: one gate row of Wih and Whh ----
  float wih[HH];
  float whh[HH];
  float bias = 0.0f;

  if (tid < NG) {
    const float4* wr = (const float4*)(Wih + (size_t)l * NG * HH + (size_t)tid * HH);
    const float4* ur = (const float4*)(Whh + (size_t)l * NG * HH + (size_t)tid * HH);
#pragma unroll
    for (int k = 0; k < 25; ++k) {
      float4 a = wr[k];
      wih[4*k+0] = a.x; wih[4*k+1] = a.y; wih[4*k+2] = a.z; wih[4*k+3] = a.w;
    }
#pragma unroll
    for (int k = 0; k < 25; ++k) {
      float4 b = ur[k];
      whh[4*k+0] = b.x; whh[4*k+1] = b.y; whh[4*k+2] = b.z; whh[4*k+3] = b.w;
    }
    bias = bih[l * NG + tid] + bhh[l * NG + tid];
  }

  // output projection weights (last layer only)
  float4 wo = make_float4(0.f, 0.f, 0.f, 0.f);
  float bo = 0.f;
  if (l == NL - 1) {
    if (tid < 250) {
      int row = tid / 25, kq = tid % 25;
      wo = ((const float4*)(Wout + row * HH))[kq];
    }
    if (tid < NOUT) bo = bout[tid];
  }

  float c = 0.f;                 // cell state, thread tid<100 owns c[tid]
  if (tid < HH) hbuf[tid] = 0.f; // h0 = 0
  __syncthreads();

  for (int t = 0; t < TT; ++t) {
    // ---- phase X: acquire x_t ----
    if (l == 0) {
      if (tid < HH) xbuf[tid] = input[t * HH + tid];
    } else {
      const int* fl = flags + (l - 1) * TT + t;
      while (__hip_atomic_load(fl, __ATOMIC_ACQUIRE, __HIP_MEMORY_SCOPE_AGENT) == 0) {
      }
      if (tid < HH) xbuf[tid] = xstage[((size_t)(l - 1) * TT + t) * HH + tid];
    }
    __syncthreads();

    // ---- phase G: gates = bias + Wih@x_t + Whh@h_{t-1}, then activation ----
    if (tid < NG) {
      float acc = bias;
      const float4* x4 = (const float4*)xbuf;  // uniform-address reads: HW broadcast
      const float4* h4 = (const float4*)hbuf;
#pragma unroll
      for (int k = 0; k < 25; ++k) {
        float4 xv = x4[k];
        acc = fmaf(wih[4*k+0], xv.x, acc);
        acc = fmaf(wih[4*k+1], xv.y, acc);
        acc = fmaf(wih[4*k+2], xv.z, acc);
        acc = fmaf(wih[4*k+3], xv.w, acc);
      }
#pragma unroll
      for (int k = 0; k < 25; ++k) {
        float4 hv = h4[k];
        acc = fmaf(whh[4*k+0], hv.x, acc);
        acc = fmaf(whh[4*k+1], hv.y, acc);
        acc = fmaf(whh[4*k+2], hv.z, acc);
        acc = fmaf(whh[4*k+3], hv.w, acc);
      }
      float v;
      if (tid < 2 * HH || tid >= 3 * HH) {
        v = 1.f / (1.f + __expf(-acc));  // i, f, o : sigmoid
      } else {
        v = tanhf(acc);                  // g : tanh
      }
      gact[tid] = v;
    }
    __syncthreads();

    // ---- phase E: elementwise state update; stage output for next layer ----
    if (tid < HH) {
      float ig = gact[tid];
      float fg = gact[HH + tid];
      float gg = gact[2 * HH + tid];
      float og = gact[3 * HH + tid];
      c = fg * c + ig * gg;
      float h = og * tanhf(c);
      hbuf[tid] = h;
      if (l < NL - 1) {
        // inter-layer ReLU applied by the producer
        xstage[((size_t)l * TT + t) * HH + tid] = fmaxf(h, 0.f);
      }
    }
    if (l < NL - 1) __threadfence();  // make staged x visible device-wide
    __syncthreads();

    if (l < NL - 1) {
      if (tid == 0) {
        __hip_atomic_store(flags + l * TT + t, 1, __ATOMIC_RELEASE,
                           __HIP_MEMORY_SCOPE_AGENT);
      }
    } else {
      // ---- fused output projection: out[t] = sigmoid(Wout @ h_t + bout) ----
      if (tid < 250) {
        int kq = tid % 25;
        const float4* h4 = (const float4*)hbuf;
        float4 hv = h4[kq];
        pacc[tid] = wo.x * hv.x + wo.y * hv.y + wo.z * hv.z + wo.w * hv.w;
      }
      __syncthreads();
      if (tid < NOUT) {
        float s = bo;
#pragma unroll
        for (int p = 0; p < 25; ++p) s += pacc[tid * 25 + p];
        out[t * NOUT + tid] = 1.f / (1.f + __expf(-s));
      }
    }
  }
}

extern "C" void kernel_launch(void* const* d_in, const int* in_sizes, int n_in,
                              void* d_out, int out_size, void* d_ws, size_t ws_size,
                              hipStream_t stream) {
  const float* input = (const float*)d_in[0];
  const float* Wih   = (const float*)d_in[1];
  const float* Whh   = (const float*)d_in[2];
  const float* bih   = (const float*)d_in[3];
  const float* bhh   = (const float*)d_in[4];
  const float* Wout  = (const float*)d_in[5];
  const float* bout  = (const float*)d_in[6];
  float* out = (float*)d_out;

  // workspace layout: [0,2048) flags (4 layers * 100 ints = 1600B used),
  //                   [2048, 2048+160000) xstage (4*100*100 floats)
  int* flags = (int*)d_ws;
  float* xstage = (float*)((char*)d_ws + 2048);

  // flags must be zero at kernel start on EVERY call (graph replays included)
  hipMemsetAsync(d_ws, 0, 2048, stream);

  lstm_pipe_kernel<<<dim3(NL), dim3(512), 0, stream>>>(
      input, Wih, Whh, bih, bhh, Wout, bout, out, flags, xstage);
}

// Round 2
// 225.541 us; speedup vs baseline: 2.0888x; 2.0888x over previous
//
#include <hip/hip_runtime.h>

#define TT 100
#define HH 100
#define NL 5
#define NOUT 10
#define NG 400        // 4*H gate rows
#define CC 10         // timesteps per inter-layer handoff chunk
#define NC (TT / CC)  // 10 chunks

__device__ __forceinline__ float fast_sigmoid(float x) {
  return 1.f / (1.f + __expf(-x));
}
__device__ __forceinline__ float fast_tanh(float x) {
  float xc = fminf(fmaxf(x, -9.f), 9.f);
  float e2 = __expf(2.f * xc);
  return (e2 - 1.f) / (e2 + 1.f);
}

// One block per layer, wavefront-pipelined over timestep CHUNKS.
// Thread r<400 owns gate row r: Wih row + Whh row live in VGPRs all 100 steps.
__launch_bounds__(512, 2)
__global__ void lstm_pipe_kernel(
    const float* __restrict__ input,   // [T, H]
    const float* __restrict__ Wih,     // [L, 4H, H]
    const float* __restrict__ Whh,     // [L, 4H, H]
    const float* __restrict__ bih,     // [L, 4H]
    const float* __restrict__ bhh,     // [L, 4H]
    const float* __restrict__ Wout,    // [OUT, H]
    const float* __restrict__ bout,    // [OUT]
    float* __restrict__ out,           // [T, OUT]
    int* __restrict__ flags,           // [L-1, NC] chunk-ready flags
    float* __restrict__ xstage)        // [L-1, T, H] inter-layer activations
{
  const int l = blockIdx.x;
  const int tid = threadIdx.x;

  __shared__ __align__(16) float xch[CC * HH];   // input chunk for this layer
  __shared__ __align__(16) float och[CC * HH];   // output chunk (pre-publish)
  __shared__ __align__(16) float hbuf[HH];       // h_{t-1} -> h_t
  __shared__ __align__(16) float gact[NG];       // activated gates
  __shared__ __align__(16) float pacc[256];      // projection partials (layer 4)

  // ---- persistent per-thread state: one gate row of Wih and Whh ----
  float4 wv[25];   // Wih row (100 floats)
  float4 uv[25];   // Whh row (100 floats)
  float bias = 0.0f;

  if (tid < NG) {
    const float4* wr = (const float4*)(Wih + (size_t)l * NG * HH + (size_t)tid * HH);
    const float4* ur = (const float4*)(Whh + (size_t)l * NG * HH + (size_t)tid * HH);
#pragma unroll 25
    for (int k = 0; k < 25; ++k) wv[k] = wr[k];
#pragma unroll 25
    for (int k = 0; k < 25; ++k) uv[k] = ur[k];
    bias = bih[l * NG + tid] + bhh[l * NG + tid];
  }

  // output projection weights (last layer only)
  float4 wo = make_float4(0.f, 0.f, 0.f, 0.f);
  float bo = 0.f;
  if (l == NL - 1) {
    if (tid < 250) {
      int row = tid / 25, kq = tid % 25;
      wo = ((const float4*)(Wout + row * HH))[kq];
    }
    if (tid < NOUT) bo = bout[tid];
  }

  float c = 0.f;                  // cell state, thread tid<100 owns c[tid]
  if (tid < HH) hbuf[tid] = 0.f;  // h0 = 0
  __syncthreads();

  for (int ch = 0; ch < NC; ++ch) {
    // ---- acquire input chunk into LDS (one handoff per CC steps) ----
    if (l == 0) {
      if (tid < CC * HH / 4)
        ((float4*)xch)[tid] = ((const float4*)(input + ch * CC * HH))[tid];
    } else {
      const int* fl = flags + (l - 1) * NC + ch;
      while (__hip_atomic_load(fl, __ATOMIC_ACQUIRE, __HIP_MEMORY_SCOPE_AGENT) == 0) {
      }
      const float4* src =
          (const float4*)(xstage + ((size_t)(l - 1) * TT + (size_t)ch * CC) * HH);
      if (tid < CC * HH / 4) ((float4*)xch)[tid] = src[tid];
    }
    __syncthreads();

    for (int s = 0; s < CC; ++s) {
      // ---- gates = bias + Wih@x_t + Whh@h_{t-1}, activation ----
      if (tid < NG) {
        float acc = bias;
        const float4* x4 = (const float4*)(xch + s * HH);
        const float4* h4 = (const float4*)hbuf;
#pragma unroll 25
        for (int k = 0; k < 25; ++k) {
          float4 xv = x4[k];
          acc = fmaf(wv[k].x, xv.x, acc);
          acc = fmaf(wv[k].y, xv.y, acc);
          acc = fmaf(wv[k].z, xv.z, acc);
          acc = fmaf(wv[k].w, xv.w, acc);
        }
#pragma unroll 25
        for (int k = 0; k < 25; ++k) {
          float4 hv = h4[k];
          acc = fmaf(uv[k].x, hv.x, acc);
          acc = fmaf(uv[k].y, hv.y, acc);
          acc = fmaf(uv[k].z, hv.z, acc);
          acc = fmaf(uv[k].w, hv.w, acc);
        }
        gact[tid] = (tid < 2 * HH || tid >= 3 * HH) ? fast_sigmoid(acc)
                                                    : fast_tanh(acc);
      }
      __syncthreads();

      // ---- elementwise state update ----
      if (tid < HH) {
        float ig = gact[tid];
        float fg = gact[HH + tid];
        float gg = gact[2 * HH + tid];
        float og = gact[3 * HH + tid];
        c = fg * c + ig * gg;
        float h = og * fast_tanh(c);
        hbuf[tid] = h;
        if (l < NL - 1) och[s * HH + tid] = fmaxf(h, 0.f);  // inter-layer ReLU
      }
      __syncthreads();

      if (l == NL - 1) {
        // ---- fused output projection: out[t] = sigmoid(Wout @ h_t + bout) ----
        if (tid < 250) {
          int kq = tid % 25;
          const float4* h4 = (const float4*)hbuf;
          float4 hv = h4[kq];
          pacc[tid] = wo.x * hv.x + wo.y * hv.y + wo.z * hv.z + wo.w * hv.w;
        }
        __syncthreads();
        if (tid < NOUT) {
          float ssum = bo;
#pragma unroll 25
          for (int p = 0; p < 25; ++p) ssum += pacc[tid * 25 + p];
          out[(ch * CC + s) * NOUT + tid] = fast_sigmoid(ssum);
        }
        // no barrier needed: pacc next written only after two barriers
      }
    }

    // ---- publish chunk: one coalesced write + one fence + one flag ----
    if (l < NL - 1) {
      float4* dst = (float4*)(xstage + ((size_t)l * TT + (size_t)ch * CC) * HH);
      if (tid < CC * HH / 4) dst[tid] = ((const float4*)och)[tid];
      __syncthreads();  // all lanes' stores complete (barrier drains vmcnt)
      if (tid == 0) {
        __threadfence();  // make chunk visible device-wide (L2 writeback)
        __hip_atomic_store(flags + l * NC + ch, 1, __ATOMIC_RELEASE,
                           __HIP_MEMORY_SCOPE_AGENT);
      }
    }
  }
}

extern "C" void kernel_launch(void* const* d_in, const int* in_sizes, int n_in,
                              void* d_out, int out_size, void* d_ws, size_t ws_size,
                              hipStream_t stream) {
  const float* input = (const float*)d_in[0];
  const float* Wih   = (const float*)d_in[1];
  const float* Whh   = (const float*)d_in[2];
  const float* bih   = (const float*)d_in[3];
  const float* bhh   = (const float*)d_in[4];
  const float* Wout  = (const float*)d_in[5];
  const float* bout  = (const float*)d_in[6];
  float* out = (float*)d_out;

  // workspace: [0,2048) flags ((L-1)*NC = 40 ints used),
  //            [2048, 2048+160000) xstage (4*100*100 floats)
  int* flags = (int*)d_ws;
  float* xstage = (float*)((char*)d_ws + 2048);

  // flags must be zero at kernel start on EVERY call (graph replays included)
  hipMemsetAsync(d_ws, 0, 2048, stream);

  lstm_pipe_kernel<<<dim3(NL), dim3(512), 0, stream>>>(
      input, Wih, Whh, bih, bhh, Wout, bout, out, flags, xstage);
}